// Round 12
// baseline (3301.263 us; speedup 1.0000x reference)
//
#include <hip/hip_runtime.h>
#include <stdint.h>

// LEM recurrent net, MI355X persistent kernel, round 12.
// = Round 11 (verified 2.066ms) with the sync chain cut to the data-
// dependency minimum:
//  - ONE block barrier per phase (the red reduce). The post-store and
//    post-poll barriers are removed.
//  - Per-storing-wave flags: gf[c*2+rtl], set by each kh==0 wave right
//    after ITS OWN store's vmcnt(0) drain. Invariant: the red barrier
//    already certifies all 4 waves consumed their state loads before kh0
//    proceeds, so kh0's flag certifies the whole block.
//  - Every wave polls all 48 group flags independently (lanes 0..47, one
//    coalesced load) and proceeds the instant it observes completion.
// Geometry etc = R11: NGRP=8 x CBLK=24 = 192 blocks x 256 thr, waves =
// rtl{0,1} x kh{0,1}, 1 block/CU. W_hid in LDS; W_inp pinned in regs; W_z
// streamed cached; x folded into GEMMs via XF; state bf16 chunks
// [kt:24][rt:16][kg:4][r16:16][e:8], uncached sc0 sc1; coalesced
// transpose-stores; deep counted-vmcnt pipelines.

#define NINP 128
#define NHID 768
#define NOUT 128
#define T_STEPS 256
#define BATCH 256

#define NGRP 8
#define CBLK 24
#define NBLK 192
#define NTHR 256
#define NFLG (CBLK * 2)         // 48 flags per group-phase

#define NHTILES 144             // W_hid LDS tiles: [ct:2][seg:3][kt:24]
#define SBUF 196608             // bf16 elems per state buffer (384KB)
#define WZ_ELEMS (1152 * 512)
#define WI_ELEMS (768 * 512)

typedef short bf16x8 __attribute__((ext_vector_type(8)));
typedef float f32x4 __attribute__((ext_vector_type(4)));

__device__ __forceinline__ unsigned short f2b(float f) {
  union { float f; unsigned u; } x; x.f = f;
  return (unsigned short)((x.u + 0x7fffu + ((x.u >> 16) & 1u)) >> 16);  // RNE
}
__device__ __forceinline__ float b2f(unsigned short h) {
  union { unsigned u; float f; } x; x.u = ((unsigned)h) << 16; return x.f;
}
__device__ __forceinline__ float fsig(float x) { return 1.0f / (1.0f + __expf(-x)); }
__device__ __forceinline__ float ftanh(float x) {
  float e = __expf(2.0f * x);
  return 1.0f - 2.0f / (e + 1.0f);
}

#define MFMA16(a, b, c) __builtin_amdgcn_mfma_f32_16x16x32_bf16(a, b, c, 0, 0, 0)

#define AL32(p) __hip_atomic_load((const unsigned*)(p), __ATOMIC_RELAXED, __HIP_MEMORY_SCOPE_AGENT)
#define AS32(p, v) __hip_atomic_store((unsigned*)(p), (v), __ATOMIC_RELAXED, __HIP_MEMORY_SCOPE_AGENT)

// uncached (device-coherent) 16B load -> bf16x8; valid after s_waitcnt
__device__ __forceinline__ void uld16(bf16x8* dst, const unsigned short* addr) {
  asm volatile("global_load_dwordx4 %0, %1, off sc0 sc1" : "=v"(*dst) : "v"(addr));
}
// cached 16B load -> bf16x8 (read-only data), manually counted
__device__ __forceinline__ void cld16(bf16x8* dst, const unsigned short* addr) {
  asm volatile("global_load_dwordx4 %0, %1, off" : "=v"(*dst) : "v"(addr));
}
// uncached (device-coherent) 16B store
__device__ __forceinline__ void ust16(unsigned short* addr, bf16x8 v) {
  asm volatile("global_store_dwordx4 %0, %1, off sc0 sc1" :: "v"(addr), "v"(v) : "memory");
}
#define WAITV(N) do { \
  asm volatile("s_waitcnt vmcnt(" #N ")" ::: "memory"); \
  __builtin_amdgcn_sched_barrier(0); } while (0)

__device__ __forceinline__ void split8(const float* p, bf16x8* hi, bf16x8* lo) {
  union { bf16x8 v; unsigned short s[8]; } H, L;
#pragma unroll
  for (int e = 0; e < 8; ++e) {
    float v = p[e];
    unsigned short h = f2b(v);
    H.s[e] = h;
    L.s[e] = f2b(v - b2f(h));
  }
  *hi = H.v; *lo = L.v;
}

// ---- prep 1: convert W_z / W_inp to bf16 fragment tiles ----
__global__ __launch_bounds__(256) void conv_w(
    const float* __restrict__ W_z, const float* __restrict__ W_inp,
    unsigned short* __restrict__ Wz, unsigned short* __restrict__ Wi) {
  int idx = blockIdx.x * 256 + threadIdx.x;
  int t = idx >> 9, r = idx & 511;
  int ll = r >> 3, e = r & 7;
  int col16 = ll & 15;
  int kk = ((ll >> 4) * 8) + e;
  if (t < 1152) {
    int kt = t % 24, ct = (t / 24) & 1, c = t / 48;
    Wz[idx] = f2b(W_z[(size_t)(c * 32 + ct * 16 + col16) * NHID + kt * 32 + kk]);
  } else {
    int u = t - 1152;
    int xkt = u & 3, ct = (u >> 2) & 1, seg = (u >> 3) & 3, c = u >> 5;
    Wi[(size_t)u * 512 + r] =
        f2b(W_inp[(size_t)(seg * NHID + c * 32 + ct * 16 + col16) * NINP + xkt * 32 + kk]);
  }
}

// ---- prep 2: convert x to hi/lo bf16 chunk layout ----
__global__ __launch_bounds__(256) void xprep(
    const float* __restrict__ x, unsigned short* __restrict__ XF) {
  int gid = blockIdx.x * 256 + threadIdx.x;
  int lane = gid & 63;
  int rtx = (gid >> 6) & 15;
  int xkt = (gid >> 10) & 3;
  int t = gid >> 12;
  int kg = lane >> 4, r16 = lane & 15;
  int row = rtx * 16 + r16;
  bf16x8 hi, lo;
  split8(x + ((size_t)t * BATCH + row) * NINP + xkt * 32 + kg * 8, &hi, &lo);
  size_t lo_off = (size_t)kg * 128 + r16 * 8;
  *(bf16x8*)(XF + ((((size_t)t * 2 + 0) * 4 + xkt) * 16 + rtx) * 512 + lo_off) = hi;
  *(bf16x8*)(XF + ((((size_t)t * 2 + 1) * 4 + xkt) * 16 + rtx) * 512 + lo_off) = lo;
}

__global__ __launch_bounds__(NTHR, 1) void lem_kernel(
    const float* __restrict__ b_inp,   // [4*NHID]
    const float* __restrict__ W_hid,   // [3*NHID][NHID]
    const float* __restrict__ b_hid,   // [3*NHID]
    const float* __restrict__ b_z,     // [NHID]
    const float* __restrict__ W_cls,   // [NOUT][NHID]
    const float* __restrict__ b_cls,   // [NOUT]
    float* __restrict__ out,           // [B][NOUT]
    unsigned short* __restrict__ Y,    // bf16 state, chunk layout
    unsigned short* __restrict__ Z,
    unsigned* __restrict__ flags,      // per group: A[48]@0, B[48]@128
    const unsigned short* __restrict__ Wz,
    const unsigned short* __restrict__ Wi,
    const unsigned short* __restrict__ XF)
{
  __shared__ unsigned short wlds[NHTILES * 512];   // 144 KB
  __shared__ float red[128 * 24];                  // 12 KB reduce buffer
  __shared__ unsigned short zt[2 * 512];           // 2 KB transpose tiles

  const int tid = threadIdx.x;
  const int l   = tid & 63;
  const int w   = tid >> 6;              // wave 0..3
  const int rtl = w & 1;                 // row-tile local (0,1)
  const int kh  = w >> 1;                // K-half (0,1)
  const int g   = blockIdx.x / CBLK;
  const int c   = blockIdx.x % CBLK;
  const int colbase = c * 32;
  const int lc  = l & 15;
  const int kg8 = (l >> 4) * 8;
  const int laneoff = (l >> 4) * 128 + lc * 8;
  const int rtg = g * 2 + rtl;           // global row-tile (16 rows)
  const int r16b = (l >> 4) * 4;

  // ---- one-time: pack W_hid slice into LDS: tile=(ct*3+seg)*24+kt ----
  for (int idx = tid; idx < NHTILES * 512; idx += NTHR) {
    int t = idx >> 9;
    int r = idx & 511;
    int ll = r >> 3, e = r & 7;
    int col16 = ll & 15;
    int kk = ((ll >> 4) * 8) + e;
    int kt = t % 24, cs = t / 24;
    int ct = cs / 3, seg = cs % 3;
    wlds[idx] = f2b(W_hid[(size_t)(seg * NHID + colbase + ct * 16 + col16) * NHID + kt * 32 + kk]);
  }

#define LDSB(t) (*(const bf16x8*)&wlds[((t) << 9) + (l << 3)])

  // biases per ct
  float c1[2], c2[2], cy[2], cz[2];
#pragma unroll
  for (int ct = 0; ct < 2; ++ct) {
    int col = colbase + ct * 16 + lc;
    c1[ct] = b_inp[col] + b_hid[col];
    c2[ct] = b_inp[NHID + col] + b_hid[NHID + col];
    cy[ct] = b_inp[3 * NHID + col] + b_hid[2 * NHID + col];
    cz[ct] = b_inp[2 * NHID + col] + b_z[col];
  }
  unsigned* gfA = flags + g * 256;
  unsigned* gfB = gfA + 128;
  const int khb = kh * 12;               // this wave's K-half base (kt units)
  // coalesced store chunk bases (block c's 32 cols == chunk kt=c)
  unsigned short* Zc = Z + (size_t)(c * 16 + rtg) * 512;
  unsigned short* Yc = Y + (size_t)(c * 16 + rtg) * 512;

  // ---- pin step-invariant W_inp fragments in registers ----
  bf16x8 wifA[3][2][2];                  // [hseg][ct][xk2]; hseg2 -> W_inp seg3
  bf16x8 wiB[2][2];                      // seg2 for phase B
#pragma unroll
  for (int hseg = 0; hseg < 3; ++hseg) {
    int wseg = (hseg == 2) ? 3 : hseg;
#pragma unroll
    for (int ct = 0; ct < 2; ++ct)
#pragma unroll
      for (int xk2 = 0; xk2 < 2; ++xk2)
        cld16(&wifA[hseg][ct][xk2],
              Wi + (size_t)((((c * 4 + wseg) * 2 + ct) * 4) + (kh * 2 + xk2)) * 512 + l * 8);
  }
#pragma unroll
  for (int ct = 0; ct < 2; ++ct)
#pragma unroll
    for (int xk2 = 0; xk2 < 2; ++xk2)
      cld16(&wiB[ct][xk2],
            Wi + (size_t)((((c * 4 + 2) * 2 + ct) * 4) + (kh * 2 + xk2)) * 512 + l * 8);

  bf16x8 xa[4];                          // [xk2*2 + hl] for this wave's 2 xkts
#define ISSUE_XA(sidx) do { \
    cld16(&xa[0], XF + ((((size_t)(sidx) * 2 + 0) * 4 + (kh * 2 + 0)) * 16 + rtg) * 512 + laneoff); \
    cld16(&xa[1], XF + ((((size_t)(sidx) * 2 + 1) * 4 + (kh * 2 + 0)) * 16 + rtg) * 512 + laneoff); \
    cld16(&xa[2], XF + ((((size_t)(sidx) * 2 + 0) * 4 + (kh * 2 + 1)) * 16 + rtg) * 512 + laneoff); \
    cld16(&xa[3], XF + ((((size_t)(sidx) * 2 + 1) * 4 + (kh * 2 + 1)) * 16 + rtg) * 512 + laneoff); } while (0)

  ISSUE_XA(0);
  WAITV(0);
  __syncthreads();                       // LDS W_hid ready; all vmem drained

  f32x4 yloc[2], zloc[2], msb[2];
#pragma unroll
  for (int ct = 0; ct < 2; ++ct) { yloc[ct] = f32x4{0,0,0,0}; zloc[ct] = f32x4{0,0,0,0}; }

  float* rp = red + (rtl * 64 + l) * 24;           // 96B stride, 16B aligned
  unsigned short* trow = zt + rtl * 512;           // kh==0 waves only

  bf16x8 ybufs[6][2];
  bf16x8 zbuf[6];
  bf16x8 wzf[6][2];
  const unsigned short* wzb0 = Wz + (size_t)((c * 2 + 0) * 24) * 512 + l * 8;
  const unsigned short* wzb1 = Wz + (size_t)((c * 2 + 1) * 24) * 512 + l * 8;

#define ISSUE_Y(slot, j) do { \
    int kt_ = khb + 2 * (j); \
    uld16(&ybufs[slot][0], Y + (size_t)(kt_ * 16 + rtg) * 512 + laneoff); \
    uld16(&ybufs[slot][1], Y + (size_t)((kt_ + 1) * 16 + rtg) * 512 + laneoff); } while (0)

#define ISSUE_Z(slot, j) do { \
    int kt_ = khb + (j); \
    uld16(&zbuf[slot], Z + (size_t)(kt_ * 16 + rtg) * 512 + laneoff); \
    cld16(&wzf[slot][0], wzb0 + (size_t)kt_ * 512); \
    cld16(&wzf[slot][1], wzb1 + (size_t)kt_ * 512); } while (0)

// every wave polls all 48 group-phase flags; proceeds when all >= tgt
#define POLL(gf, tgt) do { \
    const unsigned* fp_ = (gf) + (l < NFLG ? l : 0); \
    while (true) { \
      unsigned v_ = AL32(fp_); \
      if (__all((l >= NFLG) || (v_ >= (unsigned)(tgt)))) break; \
      __builtin_amdgcn_s_sleep(1); \
    } } while (0)

  for (int s = 0; s < T_STEPS; ++s) {
    // ===== phase A: h = y@W_hid^T + x@W_inp^T (partial K per wave) =====
    f32x4 h[3][2];
#pragma unroll
    for (int sg = 0; sg < 3; ++sg)
#pragma unroll
      for (int ct = 0; ct < 2; ++ct) h[sg][ct] = f32x4{0,0,0,0};

    // deep pipeline: all 12 uncached chunk loads in flight
    ISSUE_Y(0, 0); ISSUE_Y(1, 1); ISSUE_Y(2, 2);
    ISSUE_Y(3, 3); ISSUE_Y(4, 4); ISSUE_Y(5, 5);
    WAITV(12);                                      // xa (older) complete
#pragma unroll
    for (int xk2 = 0; xk2 < 2; ++xk2)
#pragma unroll
      for (int sg = 0; sg < 3; ++sg)
#pragma unroll
        for (int ct = 0; ct < 2; ++ct) {
          h[sg][ct] = MFMA16(xa[xk2 * 2 + 0], wifA[sg][ct][xk2], h[sg][ct]);
          h[sg][ct] = MFMA16(xa[xk2 * 2 + 1], wifA[sg][ct][xk2], h[sg][ct]);
        }
#pragma unroll
    for (int j = 0; j < 6; ++j) {
      if (j == 0) { WAITV(10); } else if (j == 1) { WAITV(8); }
      else if (j == 2) { WAITV(6); } else if (j == 3) { WAITV(4); }
      else if (j == 4) { WAITV(2); } else { WAITV(0); }
#pragma unroll
      for (int i2 = 0; i2 < 2; ++i2) {
        int ktp = khb + 2 * j + i2;
        bf16x8 a = ybufs[j][i2];
#pragma unroll
        for (int ct = 0; ct < 2; ++ct)
#pragma unroll
          for (int sg = 0; sg < 3; ++sg)
            h[sg][ct] = MFMA16(a, LDSB((ct * 3 + sg) * 24 + ktp), h[sg][ct]);
      }
    }
    if (kh == 1) {
#pragma unroll
      for (int sg = 0; sg < 3; ++sg)
#pragma unroll
        for (int ct = 0; ct < 2; ++ct)
          *(f32x4*)(rp + (sg * 2 + ct) * 4) = h[sg][ct];
    }
    __syncthreads();   // the ONE barrier: red ready AND all waves' loads consumed
    if (kh == 0) {
#pragma unroll
      for (int sg = 0; sg < 3; ++sg)
#pragma unroll
        for (int ct = 0; ct < 2; ++ct)
          h[sg][ct] += *(const f32x4*)(rp + (sg * 2 + ct) * 4);
#pragma unroll
      for (int ct = 0; ct < 2; ++ct)
#pragma unroll
        for (int i = 0; i < 4; ++i) {
          float a1 = fsig(h[0][ct][i] + c1[ct]);     // ms_dt_bar
          float a2 = fsig(h[1][ct][i] + c2[ct]);     // ms_dt
          float gg = ftanh(h[2][ct][i] + cy[ct]);
          float zn = (1.0f - a2) * zloc[ct][i] + a2 * gg;
          zloc[ct][i] = zn;
          msb[ct][i] = a1;
          int jj = ct * 16 + lc;
          trow[((jj >> 3) * 16 + r16b + i) * 8 + (jj & 7)] = f2b(zn);
        }
      asm volatile("s_waitcnt lgkmcnt(0)" ::: "memory");
      __builtin_amdgcn_sched_barrier(0);
      bf16x8 zrun = *(const bf16x8*)(trow + l * 8);
      ust16(Zc + l * 8, zrun);                       // coalesced 1KB/wave
      WAITV(0);                                      // own store at MALL
      if (l == 0) AS32(&gfA[c * 2 + rtl], (unsigned)(s + 1));
    }
    POLL(gfA, s + 1);                                // per-wave, no barrier

    // ===== phase B: az = z@W_z^T + x@W_inp2^T (partial K per wave) =====
    f32x4 az[2];
    az[0] = f32x4{0,0,0,0}; az[1] = f32x4{0,0,0,0};
    ISSUE_Z(0, 0); ISSUE_Z(1, 1); ISSUE_Z(2, 2); ISSUE_Z(3, 3); ISSUE_Z(4, 4);
#pragma unroll
    for (int xk2 = 0; xk2 < 2; ++xk2)
#pragma unroll
      for (int ct = 0; ct < 2; ++ct) {
        az[ct] = MFMA16(xa[xk2 * 2 + 0], wiB[ct][xk2], az[ct]);
        az[ct] = MFMA16(xa[xk2 * 2 + 1], wiB[ct][xk2], az[ct]);
      }
#pragma unroll
    for (int j = 0; j < 12; ++j) {
      if (j < 7) ISSUE_Z((j + 5) % 6, j + 5);
      if (j < 7) { WAITV(15); } else if (j == 7) { WAITV(12); }
      else if (j == 8) { WAITV(9); } else if (j == 9) { WAITV(6); }
      else if (j == 10) { WAITV(3); } else { WAITV(0); }
      const int sl = j % 6;
      az[0] = MFMA16(zbuf[sl], wzf[sl][0], az[0]);
      az[1] = MFMA16(zbuf[sl], wzf[sl][1], az[1]);
    }
    if (kh == 1) {
      *(f32x4*)(rp + 0) = az[0];
      *(f32x4*)(rp + 4) = az[1];
    }
    __syncthreads();   // the ONE barrier of phase B
    if (kh == 0) {
      az[0] += *(const f32x4*)(rp + 0);
      az[1] += *(const f32x4*)(rp + 4);
#pragma unroll
      for (int ct = 0; ct < 2; ++ct)
#pragma unroll
        for (int i = 0; i < 4; ++i) {
          float tt = ftanh(az[ct][i] + cz[ct]);
          float yn = (1.0f - msb[ct][i]) * yloc[ct][i] + msb[ct][i] * tt;
          yloc[ct][i] = yn;
          int jj = ct * 16 + lc;
          trow[((jj >> 3) * 16 + r16b + i) * 8 + (jj & 7)] = f2b(yn);
        }
      asm volatile("s_waitcnt lgkmcnt(0)" ::: "memory");
      __builtin_amdgcn_sched_barrier(0);
      bf16x8 yrun = *(const bf16x8*)(trow + l * 8);
      ust16(Yc + l * 8, yrun);
      WAITV(0);                                      // own store at MALL
      if (l == 0) AS32(&gfB[c * 2 + rtl], (unsigned)(s + 1));
    }
    if (s + 1 < T_STEPS) ISSUE_XA(s + 1);            // prefetch next x
    POLL(gfB, s + 1);                                // per-wave, no barrier
  }

  // ======= epilogue: out = y @ W_cls^T + b_cls (blocks c<8, own group) ====
  if (c < 8) {
    const int ocb = c * 16;
    f32x4 ao{0, 0, 0, 0};
    bf16x8 yb[12];
#pragma unroll
    for (int j = 0; j < 12; ++j)
      uld16(&yb[j], Y + (size_t)((khb + j) * 16 + rtg) * 512 + laneoff);
    WAITV(0);
#pragma unroll
    for (int j = 0; j < 12; ++j) {
      int kt = khb + j;
      bf16x8 bh, bl;
      split8(W_cls + (size_t)(ocb + lc) * NHID + kt * 32 + kg8, &bh, &bl);
      ao = MFMA16(yb[j], bh, ao);
      ao = MFMA16(yb[j], bl, ao);
    }
    if (kh == 1) *(f32x4*)(rp + 0) = ao;
    __syncthreads();
    if (kh == 0) {
      ao += *(const f32x4*)(rp + 0);
      float bc = b_cls[ocb + lc];
#pragma unroll
      for (int i = 0; i < 4; ++i)
        out[(size_t)(g * 32 + rtl * 16 + r16b + i) * NOUT + ocb + lc] = ao[i] + bc;
    }
  }
}

extern "C" void kernel_launch(void* const* d_in, const int* in_sizes, int n_in,
                              void* d_out, int out_size, void* d_ws, size_t ws_size,
                              hipStream_t stream) {
  (void)in_sizes; (void)n_in; (void)out_size; (void)ws_size;
  const float* x     = (const float*)d_in[0];
  const float* W_inp = (const float*)d_in[1];
  const float* b_inp = (const float*)d_in[2];
  const float* W_hid = (const float*)d_in[3];
  const float* b_hid = (const float*)d_in[4];
  const float* W_z   = (const float*)d_in[5];
  const float* b_z   = (const float*)d_in[6];
  const float* W_cls = (const float*)d_in[7];
  const float* b_cls = (const float*)d_in[8];

  // ws: Y(384K) Z(384K) flags(8K) Wz(1.13M) Wi(0.77M) XF(33.5M) ~= 36.2 MB
  unsigned short* Y = (unsigned short*)d_ws;
  unsigned short* Z = Y + SBUF;
  unsigned* flags = (unsigned*)(Z + SBUF);
  unsigned short* Wz = (unsigned short*)(flags + NGRP * 256);
  unsigned short* Wi = Wz + WZ_ELEMS;
  unsigned short* XF = Wi + WI_ELEMS;

  // zero state + flags each call
  hipMemsetAsync(d_ws, 0, 2 * SBUF * sizeof(unsigned short) + NGRP * 256 * sizeof(unsigned), stream);

  conv_w<<<dim3(3840), dim3(256), 0, stream>>>(W_z, W_inp, Wz, Wi);
  xprep<<<dim3(4096), dim3(256), 0, stream>>>(x, XF);

  lem_kernel<<<dim3(NBLK), dim3(NTHR), 0, stream>>>(
      b_inp, W_hid, b_hid, b_z, W_cls, b_cls,
      (float*)d_out, Y, Z, flags, Wz, Wi, XF);
}

// Round 14
// 2079.122 us; speedup vs baseline: 1.5878x; 1.5878x over previous
//
#include <hip/hip_runtime.h>
#include <stdint.h>

// LEM recurrent net, MI355X persistent kernel, round 14.
// = Round 11 (verified 2.066ms, the best verified point) + ONE contained
// change: double-buffered x prefetch. xan(s+1) is issued WITH the phase-A
// Y batch (drains at the post-store barrier, fully hidden), xa <- xan is a
// register copy in phase B after the az x-part (last consumer of xa), and
// the end-of-loop ISSUE_XA is deleted (it drained at the post-poll barrier
// on the critical path). Phase-A vmcnt ladder 14/12/10/8/6/4 (4 xan loads
// behind the 12 Y loads). Sync protocol, barriers, flags, accumulation
// order: byte-identical to R11.
// Geometry: NGRP=8 x CBLK=24 = 192 blocks x 256 thr, waves = rtl{0,1} x
// kh{0,1}, 1 block/CU. W_hid in LDS; W_inp pinned in regs; W_z streamed
// cached inside counted pipeline; x folded into GEMMs via prepped XF.
// State: bf16 chunks [kt:24][rt:16][kg:4][r16:16][e:8]; uncached sc0 sc1;
// coalesced transpose-stores; plain-store flag barrier + wave0 poll.

#define NINP 128
#define NHID 768
#define NOUT 128
#define T_STEPS 256
#define BATCH 256

#define NGRP 8
#define CBLK 24
#define NBLK 192
#define NTHR 256

#define NHTILES 144             // W_hid LDS tiles: [ct:2][seg:3][kt:24]
#define SBUF 196608             // bf16 elems per state buffer (384KB)
#define WZ_ELEMS (1152 * 512)
#define WI_ELEMS (768 * 512)

typedef short bf16x8 __attribute__((ext_vector_type(8)));
typedef float f32x4 __attribute__((ext_vector_type(4)));

__device__ __forceinline__ unsigned short f2b(float f) {
  union { float f; unsigned u; } x; x.f = f;
  return (unsigned short)((x.u + 0x7fffu + ((x.u >> 16) & 1u)) >> 16);  // RNE
}
__device__ __forceinline__ float b2f(unsigned short h) {
  union { unsigned u; float f; } x; x.u = ((unsigned)h) << 16; return x.f;
}
__device__ __forceinline__ float fsig(float x) { return 1.0f / (1.0f + __expf(-x)); }
__device__ __forceinline__ float ftanh(float x) {
  float e = __expf(2.0f * x);
  return 1.0f - 2.0f / (e + 1.0f);
}

#define MFMA16(a, b, c) __builtin_amdgcn_mfma_f32_16x16x32_bf16(a, b, c, 0, 0, 0)

#define AL32(p) __hip_atomic_load((const unsigned*)(p), __ATOMIC_RELAXED, __HIP_MEMORY_SCOPE_AGENT)
#define AS32(p, v) __hip_atomic_store((unsigned*)(p), (v), __ATOMIC_RELAXED, __HIP_MEMORY_SCOPE_AGENT)

// uncached (device-coherent) 16B load -> bf16x8; valid after s_waitcnt
__device__ __forceinline__ void uld16(bf16x8* dst, const unsigned short* addr) {
  asm volatile("global_load_dwordx4 %0, %1, off sc0 sc1" : "=v"(*dst) : "v"(addr));
}
// cached 16B load -> bf16x8 (read-only data), manually counted
__device__ __forceinline__ void cld16(bf16x8* dst, const unsigned short* addr) {
  asm volatile("global_load_dwordx4 %0, %1, off" : "=v"(*dst) : "v"(addr));
}
// uncached (device-coherent) 16B store
__device__ __forceinline__ void ust16(unsigned short* addr, bf16x8 v) {
  asm volatile("global_store_dwordx4 %0, %1, off sc0 sc1" :: "v"(addr), "v"(v) : "memory");
}
#define WAITV(N) do { \
  asm volatile("s_waitcnt vmcnt(" #N ")" ::: "memory"); \
  __builtin_amdgcn_sched_barrier(0); } while (0)

__device__ __forceinline__ void split8(const float* p, bf16x8* hi, bf16x8* lo) {
  union { bf16x8 v; unsigned short s[8]; } H, L;
#pragma unroll
  for (int e = 0; e < 8; ++e) {
    float v = p[e];
    unsigned short h = f2b(v);
    H.s[e] = h;
    L.s[e] = f2b(v - b2f(h));
  }
  *hi = H.v; *lo = L.v;
}

// ---- prep 1: convert W_z / W_inp to bf16 fragment tiles ----
__global__ __launch_bounds__(256) void conv_w(
    const float* __restrict__ W_z, const float* __restrict__ W_inp,
    unsigned short* __restrict__ Wz, unsigned short* __restrict__ Wi) {
  int idx = blockIdx.x * 256 + threadIdx.x;
  int t = idx >> 9, r = idx & 511;
  int ll = r >> 3, e = r & 7;
  int col16 = ll & 15;
  int kk = ((ll >> 4) * 8) + e;
  if (t < 1152) {
    int kt = t % 24, ct = (t / 24) & 1, c = t / 48;
    Wz[idx] = f2b(W_z[(size_t)(c * 32 + ct * 16 + col16) * NHID + kt * 32 + kk]);
  } else {
    int u = t - 1152;
    int xkt = u & 3, ct = (u >> 2) & 1, seg = (u >> 3) & 3, c = u >> 5;
    Wi[(size_t)u * 512 + r] =
        f2b(W_inp[(size_t)(seg * NHID + c * 32 + ct * 16 + col16) * NINP + xkt * 32 + kk]);
  }
}

// ---- prep 2: convert x to hi/lo bf16 chunk layout ----
__global__ __launch_bounds__(256) void xprep(
    const float* __restrict__ x, unsigned short* __restrict__ XF) {
  int gid = blockIdx.x * 256 + threadIdx.x;
  int lane = gid & 63;
  int rtx = (gid >> 6) & 15;
  int xkt = (gid >> 10) & 3;
  int t = gid >> 12;
  int kg = lane >> 4, r16 = lane & 15;
  int row = rtx * 16 + r16;
  bf16x8 hi, lo;
  split8(x + ((size_t)t * BATCH + row) * NINP + xkt * 32 + kg * 8, &hi, &lo);
  size_t lo_off = (size_t)kg * 128 + r16 * 8;
  *(bf16x8*)(XF + ((((size_t)t * 2 + 0) * 4 + xkt) * 16 + rtx) * 512 + lo_off) = hi;
  *(bf16x8*)(XF + ((((size_t)t * 2 + 1) * 4 + xkt) * 16 + rtx) * 512 + lo_off) = lo;
}

__global__ __launch_bounds__(NTHR, 1) void lem_kernel(
    const float* __restrict__ b_inp,   // [4*NHID]
    const float* __restrict__ W_hid,   // [3*NHID][NHID]
    const float* __restrict__ b_hid,   // [3*NHID]
    const float* __restrict__ b_z,     // [NHID]
    const float* __restrict__ W_cls,   // [NOUT][NHID]
    const float* __restrict__ b_cls,   // [NOUT]
    float* __restrict__ out,           // [B][NOUT]
    unsigned short* __restrict__ Y,    // bf16 state, chunk layout
    unsigned short* __restrict__ Z,
    unsigned* __restrict__ flags,      // per group: flagA[24]@0, flagB[24]@64
    const unsigned short* __restrict__ Wz,
    const unsigned short* __restrict__ Wi,
    const unsigned short* __restrict__ XF)
{
  __shared__ unsigned short wlds[NHTILES * 512];   // 144 KB
  __shared__ float red[128 * 24];                  // 12 KB reduce buffer
  __shared__ unsigned short zt[2 * 512];           // 2 KB transpose tiles

  const int tid = threadIdx.x;
  const int l   = tid & 63;
  const int w   = tid >> 6;              // wave 0..3
  const int rtl = w & 1;                 // row-tile local (0,1)
  const int kh  = w >> 1;                // K-half (0,1)
  const int g   = blockIdx.x / CBLK;
  const int c   = blockIdx.x % CBLK;
  const int colbase = c * 32;
  const int lc  = l & 15;
  const int kg8 = (l >> 4) * 8;
  const int laneoff = (l >> 4) * 128 + lc * 8;
  const int rtg = g * 2 + rtl;           // global row-tile (16 rows)
  const int r16b = (l >> 4) * 4;

  // ---- one-time: pack W_hid slice into LDS: tile=(ct*3+seg)*24+kt ----
  for (int idx = tid; idx < NHTILES * 512; idx += NTHR) {
    int t = idx >> 9;
    int r = idx & 511;
    int ll = r >> 3, e = r & 7;
    int col16 = ll & 15;
    int kk = ((ll >> 4) * 8) + e;
    int kt = t % 24, cs = t / 24;
    int ct = cs / 3, seg = cs % 3;
    wlds[idx] = f2b(W_hid[(size_t)(seg * NHID + colbase + ct * 16 + col16) * NHID + kt * 32 + kk]);
  }

#define LDSB(t) (*(const bf16x8*)&wlds[((t) << 9) + (l << 3)])

  // biases per ct
  float c1[2], c2[2], cy[2], cz[2];
#pragma unroll
  for (int ct = 0; ct < 2; ++ct) {
    int col = colbase + ct * 16 + lc;
    c1[ct] = b_inp[col] + b_hid[col];
    c2[ct] = b_inp[NHID + col] + b_hid[NHID + col];
    cy[ct] = b_inp[3 * NHID + col] + b_hid[2 * NHID + col];
    cz[ct] = b_inp[2 * NHID + col] + b_z[col];
  }
  unsigned* gfA = flags + g * 128;
  unsigned* gfB = gfA + 64;
  const int khb = kh * 12;               // this wave's K-half base (kt units)
  // coalesced store chunk bases (block c's 32 cols == chunk kt=c)
  unsigned short* Zc = Z + (size_t)(c * 16 + rtg) * 512;
  unsigned short* Yc = Y + (size_t)(c * 16 + rtg) * 512;

  // ---- pin step-invariant W_inp fragments in registers ----
  bf16x8 wifA[3][2][2];                  // [hseg][ct][xk2]; hseg2 -> W_inp seg3
  bf16x8 wiB[2][2];                      // seg2 for phase B
#pragma unroll
  for (int hseg = 0; hseg < 3; ++hseg) {
    int wseg = (hseg == 2) ? 3 : hseg;
#pragma unroll
    for (int ct = 0; ct < 2; ++ct)
#pragma unroll
      for (int xk2 = 0; xk2 < 2; ++xk2)
        cld16(&wifA[hseg][ct][xk2],
              Wi + (size_t)((((c * 4 + wseg) * 2 + ct) * 4) + (kh * 2 + xk2)) * 512 + l * 8);
  }
#pragma unroll
  for (int ct = 0; ct < 2; ++ct)
#pragma unroll
    for (int xk2 = 0; xk2 < 2; ++xk2)
      cld16(&wiB[ct][xk2],
            Wi + (size_t)((((c * 4 + 2) * 2 + ct) * 4) + (kh * 2 + xk2)) * 512 + l * 8);

  bf16x8 xa[4];                          // current-step x fragments
  bf16x8 xan[4];                         // next-step x fragments (prefetch)
#define ISSUE_XBUF(buf, sidx) do { \
    cld16(&buf[0], XF + ((((size_t)(sidx) * 2 + 0) * 4 + (kh * 2 + 0)) * 16 + rtg) * 512 + laneoff); \
    cld16(&buf[1], XF + ((((size_t)(sidx) * 2 + 1) * 4 + (kh * 2 + 0)) * 16 + rtg) * 512 + laneoff); \
    cld16(&buf[2], XF + ((((size_t)(sidx) * 2 + 0) * 4 + (kh * 2 + 1)) * 16 + rtg) * 512 + laneoff); \
    cld16(&buf[3], XF + ((((size_t)(sidx) * 2 + 1) * 4 + (kh * 2 + 1)) * 16 + rtg) * 512 + laneoff); } while (0)

  ISSUE_XBUF(xa, 0);
  WAITV(0);
  __syncthreads();                       // LDS W_hid ready; all vmem drained

  f32x4 yloc[2], zloc[2], msb[2];
#pragma unroll
  for (int ct = 0; ct < 2; ++ct) { yloc[ct] = f32x4{0,0,0,0}; zloc[ct] = f32x4{0,0,0,0}; }

  float* rp = red + (rtl * 64 + l) * 24;           // 96B stride, 16B aligned
  unsigned short* trow = zt + rtl * 512;           // kh==0 waves only

  bf16x8 ybufs[6][2];
  bf16x8 zbuf[6];
  bf16x8 wzf[6][2];
  const unsigned short* wzb0 = Wz + (size_t)((c * 2 + 0) * 24) * 512 + l * 8;
  const unsigned short* wzb1 = Wz + (size_t)((c * 2 + 1) * 24) * 512 + l * 8;

#define ISSUE_Y(slot, j) do { \
    int kt_ = khb + 2 * (j); \
    uld16(&ybufs[slot][0], Y + (size_t)(kt_ * 16 + rtg) * 512 + laneoff); \
    uld16(&ybufs[slot][1], Y + (size_t)((kt_ + 1) * 16 + rtg) * 512 + laneoff); } while (0)

#define ISSUE_Z(slot, j) do { \
    int kt_ = khb + (j); \
    uld16(&zbuf[slot], Z + (size_t)(kt_ * 16 + rtg) * 512 + laneoff); \
    cld16(&wzf[slot][0], wzb0 + (size_t)kt_ * 512); \
    cld16(&wzf[slot][1], wzb1 + (size_t)kt_ * 512); } while (0)

  for (int s = 0; s < T_STEPS; ++s) {
    // ===== phase A: h = y@W_hid^T + x@W_inp^T (partial K per wave) =====
    f32x4 h[3][2];
#pragma unroll
    for (int sg = 0; sg < 3; ++sg)
#pragma unroll
      for (int ct = 0; ct < 2; ++ct) h[sg][ct] = f32x4{0,0,0,0};

    // deep pipeline: 12 uncached chunk loads + 4 next-x prefetch in flight
    ISSUE_Y(0, 0); ISSUE_Y(1, 1); ISSUE_Y(2, 2);
    ISSUE_Y(3, 3); ISSUE_Y(4, 4); ISSUE_Y(5, 5);
    ISSUE_XBUF(xan, (s + 1 < T_STEPS) ? (s + 1) : s);   // hidden: drains at post-store sync
    // x-part (xa valid: pre-loop load or phase-B copy)
#pragma unroll
    for (int xk2 = 0; xk2 < 2; ++xk2)
#pragma unroll
      for (int sg = 0; sg < 3; ++sg)
#pragma unroll
        for (int ct = 0; ct < 2; ++ct) {
          h[sg][ct] = MFMA16(xa[xk2 * 2 + 0], wifA[sg][ct][xk2], h[sg][ct]);
          h[sg][ct] = MFMA16(xa[xk2 * 2 + 1], wifA[sg][ct][xk2], h[sg][ct]);
        }
#pragma unroll
    for (int j = 0; j < 6; ++j) {
      if (j == 0) { WAITV(14); } else if (j == 1) { WAITV(12); }
      else if (j == 2) { WAITV(10); } else if (j == 3) { WAITV(8); }
      else if (j == 4) { WAITV(6); } else { WAITV(4); }
#pragma unroll
      for (int i2 = 0; i2 < 2; ++i2) {
        int ktp = khb + 2 * j + i2;
        bf16x8 a = ybufs[j][i2];
#pragma unroll
        for (int ct = 0; ct < 2; ++ct)
#pragma unroll
          for (int sg = 0; sg < 3; ++sg)
            h[sg][ct] = MFMA16(a, LDSB((ct * 3 + sg) * 24 + ktp), h[sg][ct]);
      }
    }
    if (kh == 1) {
#pragma unroll
      for (int sg = 0; sg < 3; ++sg)
#pragma unroll
        for (int ct = 0; ct < 2; ++ct)
          *(f32x4*)(rp + (sg * 2 + ct) * 4) = h[sg][ct];
    }
    __syncthreads();
    if (kh == 0) {
#pragma unroll
      for (int sg = 0; sg < 3; ++sg)
#pragma unroll
      for (int ct = 0; ct < 2; ++ct)
          h[sg][ct] += *(const f32x4*)(rp + (sg * 2 + ct) * 4);
#pragma unroll
      for (int ct = 0; ct < 2; ++ct)
#pragma unroll
        for (int i = 0; i < 4; ++i) {
          float a1 = fsig(h[0][ct][i] + c1[ct]);     // ms_dt_bar
          float a2 = fsig(h[1][ct][i] + c2[ct]);     // ms_dt
          float gg = ftanh(h[2][ct][i] + cy[ct]);
          float zn = (1.0f - a2) * zloc[ct][i] + a2 * gg;
          zloc[ct][i] = zn;
          msb[ct][i] = a1;
          int jj = ct * 16 + lc;
          trow[((jj >> 3) * 16 + r16b + i) * 8 + (jj & 7)] = f2b(zn);
        }
      asm volatile("s_waitcnt lgkmcnt(0)" ::: "memory");
      __builtin_amdgcn_sched_barrier(0);
      bf16x8 zrun = *(const bf16x8*)(trow + l * 8);
      ust16(Zc + l * 8, zrun);                       // coalesced 1KB/wave
    }
    __syncthreads();                                  // drain z-stores (+xan)
    if (tid == 0) AS32(&gfA[c], (unsigned)(s + 1));
    if (w == 0) {
      const unsigned* fp = gfA + (l < CBLK ? l : 0);
      while (true) {
        unsigned v = AL32(fp);
        if (__all((l >= CBLK) || (v >= (unsigned)(s + 1)))) break;
        __builtin_amdgcn_s_sleep(1);
      }
    }
    __syncthreads();

    // ===== phase B: az = z@W_z^T + x@W_inp2^T (partial K per wave) =====
    f32x4 az[2];
    az[0] = f32x4{0,0,0,0}; az[1] = f32x4{0,0,0,0};
    ISSUE_Z(0, 0); ISSUE_Z(1, 1); ISSUE_Z(2, 2); ISSUE_Z(3, 3); ISSUE_Z(4, 4);
#pragma unroll
    for (int xk2 = 0; xk2 < 2; ++xk2)
#pragma unroll
      for (int ct = 0; ct < 2; ++ct) {
        az[ct] = MFMA16(xa[xk2 * 2 + 0], wiB[ct][xk2], az[ct]);
        az[ct] = MFMA16(xa[xk2 * 2 + 1], wiB[ct][xk2], az[ct]);
      }
    // xa dead from here: promote prefetched next-step x (register copies;
    // xan completed at the phase-A post-store barrier)
    xa[0] = xan[0]; xa[1] = xan[1]; xa[2] = xan[2]; xa[3] = xan[3];
#pragma unroll
    for (int j = 0; j < 12; ++j) {
      if (j < 7) ISSUE_Z((j + 5) % 6, j + 5);
      if (j < 7) { WAITV(15); } else if (j == 7) { WAITV(12); }
      else if (j == 8) { WAITV(9); } else if (j == 9) { WAITV(6); }
      else if (j == 10) { WAITV(3); } else { WAITV(0); }
      const int sl = j % 6;
      az[0] = MFMA16(zbuf[sl], wzf[sl][0], az[0]);
      az[1] = MFMA16(zbuf[sl], wzf[sl][1], az[1]);
    }
    if (kh == 1) {
      *(f32x4*)(rp + 0) = az[0];
      *(f32x4*)(rp + 4) = az[1];
    }
    __syncthreads();
    if (kh == 0) {
      az[0] += *(const f32x4*)(rp + 0);
      az[1] += *(const f32x4*)(rp + 4);
#pragma unroll
      for (int ct = 0; ct < 2; ++ct)
#pragma unroll
        for (int i = 0; i < 4; ++i) {
          float tt = ftanh(az[ct][i] + cz[ct]);
          float yn = (1.0f - msb[ct][i]) * yloc[ct][i] + msb[ct][i] * tt;
          yloc[ct][i] = yn;
          int jj = ct * 16 + lc;
          trow[((jj >> 3) * 16 + r16b + i) * 8 + (jj & 7)] = f2b(yn);
        }
      asm volatile("s_waitcnt lgkmcnt(0)" ::: "memory");
      __builtin_amdgcn_sched_barrier(0);
      bf16x8 yrun = *(const bf16x8*)(trow + l * 8);
      ust16(Yc + l * 8, yrun);
    }
    __syncthreads();                                  // drain y-stores
    if (tid == 0) AS32(&gfB[c], (unsigned)(s + 1));
    if (w == 0) {
      const unsigned* fp = gfB + (l < CBLK ? l : 0);
      while (true) {
        unsigned v = AL32(fp);
        if (__all((l >= CBLK) || (v >= (unsigned)(s + 1)))) break;
        __builtin_amdgcn_s_sleep(1);
      }
    }
    __syncthreads();
  }

  // ======= epilogue: out = y @ W_cls^T + b_cls (blocks c<8, own group) ====
  if (c < 8) {
    const int ocb = c * 16;
    f32x4 ao{0, 0, 0, 0};
    bf16x8 yb[12];
#pragma unroll
    for (int j = 0; j < 12; ++j)
      uld16(&yb[j], Y + (size_t)((khb + j) * 16 + rtg) * 512 + laneoff);
    WAITV(0);
#pragma unroll
    for (int j = 0; j < 12; ++j) {
      int kt = khb + j;
      bf16x8 bh, bl;
      split8(W_cls + (size_t)(ocb + lc) * NHID + kt * 32 + kg8, &bh, &bl);
      ao = MFMA16(yb[j], bh, ao);
      ao = MFMA16(yb[j], bl, ao);
    }
    if (kh == 1) *(f32x4*)(rp + 0) = ao;
    __syncthreads();
    if (kh == 0) {
      ao += *(const f32x4*)(rp + 0);
      float bc = b_cls[ocb + lc];
#pragma unroll
      for (int i = 0; i < 4; ++i)
        out[(size_t)(g * 32 + rtl * 16 + r16b + i) * NOUT + ocb + lc] = ao[i] + bc;
    }
  }
}

extern "C" void kernel_launch(void* const* d_in, const int* in_sizes, int n_in,
                              void* d_out, int out_size, void* d_ws, size_t ws_size,
                              hipStream_t stream) {
  (void)in_sizes; (void)n_in; (void)out_size; (void)ws_size;
  const float* x     = (const float*)d_in[0];
  const float* W_inp = (const float*)d_in[1];
  const float* b_inp = (const float*)d_in[2];
  const float* W_hid = (const float*)d_in[3];
  const float* b_hid = (const float*)d_in[4];
  const float* W_z   = (const float*)d_in[5];
  const float* b_z   = (const float*)d_in[6];
  const float* W_cls = (const float*)d_in[7];
  const float* b_cls = (const float*)d_in[8];

  // ws: Y(384K) Z(384K) flags(4K) Wz(1.13M) Wi(0.77M) XF(33.5M) ~= 36.2 MB
  unsigned short* Y = (unsigned short*)d_ws;
  unsigned short* Z = Y + SBUF;
  unsigned* flags = (unsigned*)(Z + SBUF);
  unsigned short* Wz = (unsigned short*)(flags + NGRP * 128);
  unsigned short* Wi = Wz + WZ_ELEMS;
  unsigned short* XF = Wi + WI_ELEMS;

  // zero state + flags each call
  hipMemsetAsync(d_ws, 0, 2 * SBUF * sizeof(unsigned short) + NGRP * 128 * sizeof(unsigned), stream);

  conv_w<<<dim3(3840), dim3(256), 0, stream>>>(W_z, W_inp, Wz, Wi);
  xprep<<<dim3(4096), dim3(256), 0, stream>>>(x, XF);

  lem_kernel<<<dim3(NBLK), dim3(NTHR), 0, stream>>>(
      b_inp, W_hid, b_hid, b_z, W_cls, b_cls,
      (float*)d_out, Y, Z, flags, Wz, Wi, XF);
}